// Round 1
// baseline (742.666 us; speedup 1.0000x reference)
//
#include <hip/hip_runtime.h>
#include <math.h>

#define D 1024
#define EPS_COS 1e-8f
#define EP 0.001f

// One 64-lane wave per row: 64 lanes x 4 float4 = 1024 floats per operand.
// Computes dot(a,b), ||a||^2, ||b||^2, shuffle-reduces, writes exp(cos) to e[row].
__global__ __launch_bounds__(256) void row_cosexp_kernel(
    const float* __restrict__ qpos, const float* __restrict__ ipos,
    const float* __restrict__ qneg, const float* __restrict__ ineg,
    float* __restrict__ e, int n_pos, int n_total)
{
    const int row  = (int)((blockIdx.x * blockDim.x + threadIdx.x) >> 6);
    const int lane = threadIdx.x & 63;
    if (row >= n_total) return;

    const float* a;
    const float* b;
    if (row < n_pos) {
        a = qpos + (size_t)row * D;
        b = ipos + (size_t)row * D;
    } else {
        const size_t rn = (size_t)(row - n_pos);
        a = qneg + rn * D;
        b = ineg + rn * D;
    }
    const float4* a4 = (const float4*)a;
    const float4* b4 = (const float4*)b;

    float dab = 0.f, daa = 0.f, dbb = 0.f;
#pragma unroll
    for (int j = 0; j < 4; ++j) {
        const float4 av = a4[lane + 64 * j];
        const float4 bv = b4[lane + 64 * j];
        dab += av.x * bv.x + av.y * bv.y + av.z * bv.z + av.w * bv.w;
        daa += av.x * av.x + av.y * av.y + av.z * av.z + av.w * av.w;
        dbb += bv.x * bv.x + bv.y * bv.y + bv.z * bv.z + bv.w * bv.w;
    }

    // 64-lane butterfly reduction (wave = 64 on CDNA)
#pragma unroll
    for (int off = 32; off > 0; off >>= 1) {
        dab += __shfl_down(dab, off, 64);
        daa += __shfl_down(daa, off, 64);
        dbb += __shfl_down(dbb, off, 64);
    }

    if (lane == 0) {
        const float denom = fmaxf(sqrtf(daa) * sqrtf(dbb), EPS_COS);
        e[row] = __expf(dab / denom);
    }
}

// One thread per batch item: 2 pos + 23 neg exp values -> per_item, then
// block reduction + one atomicAdd per block.
__global__ __launch_bounds__(256) void combine_kernel(
    const float* __restrict__ e, float* __restrict__ out, int B, int n_pos)
{
    const int i = (int)(blockIdx.x * blockDim.x + threadIdx.x);
    float v = 0.f;
    if (i < B) {
        const float ps = e[2 * i] + e[2 * i + 1];
        const float* en = e + n_pos + 23 * (size_t)i;
        float ns = 0.f;
#pragma unroll
        for (int j = 0; j < 23; ++j) ns += en[j];
        v = (ns - ps) / (ps + ns + EP);
    }

#pragma unroll
    for (int off = 32; off > 0; off >>= 1) v += __shfl_down(v, off, 64);

    __shared__ float s[4];
    const int lane = threadIdx.x & 63;
    const int w    = threadIdx.x >> 6;
    if (lane == 0) s[w] = v;
    __syncthreads();
    if (threadIdx.x == 0) {
        const float t = s[0] + s[1] + s[2] + s[3];
        atomicAdd(out, t);
    }
}

extern "C" void kernel_launch(void* const* d_in, const int* in_sizes, int n_in,
                              void* d_out, int out_size, void* d_ws, size_t ws_size,
                              hipStream_t stream) {
    const float* qpos = (const float*)d_in[0];   // [2B, D]
    const float* qneg = (const float*)d_in[1];   // [23B, D]
    const float* ipos = (const float*)d_in[2];   // [2B, D]
    const float* ineg = (const float*)d_in[3];   // [23B, D]

    const int B       = in_sizes[0] / (2 * D);   // 4096
    const int n_pos   = 2 * B;                   // 8192
    const int n_neg   = 23 * B;                  // 94208
    const int n_total = n_pos + n_neg;           // 102400

    float* e = (float*)d_ws;                     // 102400 floats = 400 KB

    // d_out is poisoned to 0xAA before every timed launch — zero it.
    hipMemsetAsync(d_out, 0, sizeof(float), stream);

    // 4 waves per 256-thread block -> 4 rows per block
    const int rows_per_block = 256 / 64;
    const int grid1 = (n_total + rows_per_block - 1) / rows_per_block;
    row_cosexp_kernel<<<grid1, 256, 0, stream>>>(qpos, ipos, qneg, ineg, e, n_pos, n_total);

    const int grid2 = (B + 255) / 256;
    combine_kernel<<<grid2, 256, 0, stream>>>(e, (float*)d_out, B, n_pos);
}